// Round 4
// 756.658 us; speedup vs baseline: 1.0840x; 1.0840x over previous
//
#include <hip/hip_runtime.h>
#include <cmath>

// ---- TwinsBlock: B=32, H=W=56, C=256, heads=8, ws=7. fp32 I/O, bf16 MFMA ----
// R4: minimal-delta from the proven 818us baseline (R2/R3 failed at CONTAINER
// level — infra suspect). Identical memory layout, kernel set, grids, and
// stream ops to R0. Only two in-kernel changes:
//   (a) GELU erf -> tanh-sigmoid form (fc1 epilogue was ~6x the MFMA work;
//       MfmaUtil 9.7%, VALUBusy 61% on that dispatch).
//   (b) XCD-aware block swizzle in the GEMM (FETCH was 201MB vs 52MB ideal;
//       consecutive same-XCD blocks now share the A-tile panel in L2).
// LN-fold (ln_inplace_h removal) intentionally deferred until a clean run
// establishes the infra is healthy and ws_size headroom is confirmed.
typedef __bf16 bf16;
typedef __bf16 bf16x4 __attribute__((ext_vector_type(4)));
typedef __bf16 bf16x8 __attribute__((ext_vector_type(8)));
typedef float floatx4 __attribute__((ext_vector_type(4)));

constexpr int BATCH = 32;
constexpr int NTOK  = 3136;            // 56*56
constexpr int CDIM  = 256;
constexpr int MROWS = BATCH * NTOK;    // 100352
constexpr int HIDD  = 1024;
constexpr float ATTN_SCALE = 0.17677669529663689f;  // 32^-0.5

// tanh-form GELU: x * sigmoid(1.5957691*(x + 0.044715 x^3)). |err| ~3e-3,
// below the bf16 rounding already applied to h. ~6 VALU ops vs ~30 for erff.
__device__ __forceinline__ float gelu_fast(float x) {
    float p = fmaf(0.044715f * x, x * x, x);
    return __fdividef(x, 1.0f + __expf(-1.5957691216057308f * p));
}

__device__ __forceinline__ void load8(const bf16* p, float* o) {
    bf16x8 v = *reinterpret_cast<const bf16x8*>(p);
#pragma unroll
    for (int j = 0; j < 8; j++) o[j] = (float)v[j];
}

// async global->LDS, 16B per lane, wave-uniform LDS base + lane*16
__device__ __forceinline__ void gload_lds16(const void* g, void* l) {
    __builtin_amdgcn_global_load_lds(
        (const __attribute__((address_space(1))) void*)g,
        (__attribute__((address_space(3))) void*)l, 16, 0, 0);
}

// ---------------- weight convert + transpose: fp32 [K,N] -> bf16 [N,K] ----------------
__global__ __launch_bounds__(256) void wt_kernel(
    const float* __restrict__ Win, bf16* __restrict__ Wt, int Ksz, int Nsz)
{
    int id = blockIdx.x * 256 + threadIdx.x;       // over N*K, write-coalesced
    int n = id / Ksz, k = id % Ksz;
    Wt[id] = (bf16)Win[(size_t)k * Nsz + n];
}

// ---------------- fused LN (stats+apply): fp32 [M,256] -> bf16 [M,256] ----------------
__global__ __launch_bounds__(256) void ln_apply_f32_kernel(
    const float* __restrict__ X, const float* __restrict__ g,
    const float* __restrict__ b, bf16* __restrict__ Y)
{
    int tok  = (blockIdx.x * 256 + threadIdx.x) >> 6;   // one wave per token
    int lane = threadIdx.x & 63;
    const float* row = X + (size_t)tok * CDIM;
    float4 v = *reinterpret_cast<const float4*>(row + lane * 4);
    float s  = v.x + v.y + v.z + v.w;
    float ss = v.x * v.x + v.y * v.y + v.z * v.z + v.w * v.w;
#pragma unroll
    for (int off = 32; off > 0; off >>= 1) {
        s  += __shfl_xor(s,  off, 64);
        ss += __shfl_xor(ss, off, 64);
    }
    float mean = s * (1.0f / CDIM);
    float var  = ss * (1.0f / CDIM) - mean * mean;
    if (var < 0.f) var = 0.f;
    float rstd = rsqrtf(var + 1e-5f);
    float4 gg = *reinterpret_cast<const float4*>(g + lane * 4);
    float4 bb = *reinterpret_cast<const float4*>(b + lane * 4);
    bf16x4 o;
    o[0] = (bf16)((v.x - mean) * rstd * gg.x + bb.x);
    o[1] = (bf16)((v.y - mean) * rstd * gg.y + bb.y);
    o[2] = (bf16)((v.z - mean) * rstd * gg.z + bb.z);
    o[3] = (bf16)((v.w - mean) * rstd * gg.w + bb.w);
    *reinterpret_cast<bf16x4*>(Y + (size_t)tok * CDIM + lane * 4) = o;
}

// ---------------- fused LN in-place: bf16 [M,1024] (row private to wave) ----------------
__global__ __launch_bounds__(256) void ln_inplace_h_kernel(
    bf16* __restrict__ H, const float* __restrict__ g, const float* __restrict__ b)
{
    int tok  = (blockIdx.x * 256 + threadIdx.x) >> 6;
    int lane = threadIdx.x & 63;
    bf16* row = H + (size_t)tok * HIDD;
    float f[16];
    load8(row + lane * 8, f);
    load8(row + 512 + lane * 8, f + 8);
    float s = 0.f, ss = 0.f;
#pragma unroll
    for (int j = 0; j < 16; j++) { s += f[j]; ss += f[j] * f[j]; }
#pragma unroll
    for (int off = 32; off > 0; off >>= 1) {
        s  += __shfl_xor(s,  off, 64);
        ss += __shfl_xor(ss, off, 64);
    }
    float mean = s * (1.0f / HIDD);
    float var  = ss * (1.0f / HIDD) - mean * mean;
    if (var < 0.f) var = 0.f;
    float rstd = rsqrtf(var + 1e-5f);
    bf16x8 o0, o1;
#pragma unroll
    for (int j = 0; j < 8; j++) {
        o0[j] = (bf16)((f[j]     - mean) * rstd * g[lane * 8 + j]       + b[lane * 8 + j]);
        o1[j] = (bf16)((f[j + 8] - mean) * rstd * g[512 + lane * 8 + j] + b[512 + lane * 8 + j]);
    }
    *reinterpret_cast<bf16x8*>(row + lane * 8) = o0;
    *reinterpret_cast<bf16x8*>(row + 512 + lane * 8) = o1;
}

// ---------------- m97-style GEMM: out = epi( A[M,K] @ Bt[N,K]^T + bias ) ----------------
// 128x128 tile, BK=64, 4 waves (2x2), each 64x64 via 4x4 of mfma_f32_16x16x32_bf16.
// Both operands staged via global_load_lds width=16. EPI: 0 bias, 1 bias+GELU, 2 bias+resid.
// XCD swizzle: consecutive same-XCD blocks share the A-tile (nwg%8==0 for all grids:
// qkv 6*784, fc1 8*784, fc2 2*784).
template<int EPI, typename TO>
__global__ __launch_bounds__(256) void gemm_bt_kernel(
    const bf16* __restrict__ A, const bf16* __restrict__ Bt,
    const float* __restrict__ bias, const float* __restrict__ resid,
    TO* __restrict__ out, int Nsz, int Ksz)
{
    __shared__ bf16 lA[128 * 64];   // [m][k], pitch 64 (global_load_lds needs contiguity)
    __shared__ bf16 lB[128 * 64];   // [n][k]
    const int t = threadIdx.x;
    const int lane = t & 63, w = t >> 6;
    const int quad = lane >> 4, l16 = lane & 15;
    const int wm = (w >> 1) * 64, wn = (w & 1) * 64;

    const int gx   = gridDim.x;
    const int flat = blockIdx.y * gx + blockIdx.x;
    const int cpx  = (gx * gridDim.y) >> 3;            // blocks per XCD
    const int fl2  = (flat & 7) * cpx + (flat >> 3);   // bijective (nwg%8==0)
    const int bx   = fl2 % gx, by = fl2 / gx;

    const size_t m0 = (size_t)by * 128;
    const int n0 = bx * 128;
    const int srow = w * 32 + (lane >> 3);   // staging: 8 lanes per 64-elem row
    const int scol = (lane & 7) * 8;

    floatx4 acc[4][4] = {};

    for (int kc = 0; kc < Ksz; kc += 64) {
#pragma unroll
        for (int j = 0; j < 4; j++) {
            gload_lds16(A  + (m0 + srow + j * 8) * Ksz + kc + scol, &lA[(w * 32 + j * 8) * 64]);
            gload_lds16(Bt + (size_t)(n0 + srow + j * 8) * Ksz + kc + scol, &lB[(w * 32 + j * 8) * 64]);
        }
        __syncthreads();
#pragma unroll
        for (int ks = 0; ks < 64; ks += 32) {
            bf16x8 af[4], bfv[4];
#pragma unroll
            for (int i = 0; i < 4; i++) {
                af[i]  = *reinterpret_cast<const bf16x8*>(&lA[(wm + i * 16 + l16) * 64 + ks + quad * 8]);
                bfv[i] = *reinterpret_cast<const bf16x8*>(&lB[(wn + i * 16 + l16) * 64 + ks + quad * 8]);
            }
#pragma unroll
            for (int mi = 0; mi < 4; mi++)
#pragma unroll
                for (int ni = 0; ni < 4; ni++)
                    acc[mi][ni] = __builtin_amdgcn_mfma_f32_16x16x32_bf16(af[mi], bfv[ni], acc[mi][ni], 0, 0, 0);
        }
        __syncthreads();
    }

#pragma unroll
    for (int mi = 0; mi < 4; mi++) {
#pragma unroll
        for (int ni = 0; ni < 4; ni++) {
            int col = n0 + wn + ni * 16 + l16;
            float bcol = bias[col];
#pragma unroll
            for (int r = 0; r < 4; r++) {
                size_t row = m0 + wm + mi * 16 + quad * 4 + r;   // C/D: row=quad*4+reg
                float v = acc[mi][ni][r] + bcol;
                if (EPI == 1) v = gelu_fast(v);
                if (EPI == 2) v += resid[row * (size_t)Nsz + col];
                out[row * (size_t)Nsz + col] = (TO)v;
            }
        }
    }
}

// ---------------- windowed attention, one wave = one (batch, window, head) ----------------
__global__ __launch_bounds__(256) void attn_kernel(
    const bf16* __restrict__ qkv, const float* __restrict__ X,
    float* __restrict__ x1)
{
    __shared__ bf16 pbuf[4][64 * 72];   // P[i][j], per wave
    __shared__ bf16 vtbuf[4][32 * 72];  // V^T[d][j], per wave
    const int w = threadIdx.x >> 6, lane = threadIdx.x & 63;
    const int quad = lane >> 4, l16 = lane & 15;
    const int blk = blockIdx.x;
    const int hg = blk & 1, p = (blk >> 1) & 63, b = blk >> 7;
    const int h = hg * 4 + w;
    const int py = p >> 3, px = p & 7;
    const size_t gbase = (size_t)b * NTOK + py * 7 * 56 + px * 7;
    bf16* P  = pbuf[w];
    bf16* VT = vtbuf[w];

    unsigned int* vz = (unsigned int*)VT;
    for (int i = lane; i < 32 * 72 / 2; i += 64) vz[i] = 0u;

    for (int idx = lane; idx < 49 * 4; idx += 64) {
        int tk = idx >> 2, d8 = (idx & 3) * 8;
        size_t g = gbase + (tk / 7) * 56 + (tk % 7);
        bf16x8 vv = *reinterpret_cast<const bf16x8*>(qkv + g * 768 + 512 + h * 32 + d8);
#pragma unroll
        for (int j = 0; j < 8; j++) VT[(d8 + j) * 72 + tk] = vv[j];
    }

    bf16x8 qf[4], kf[4];
#pragma unroll
    for (int mt = 0; mt < 4; mt++) {
        int i = mt * 16 + l16; if (i > 48) i = 48;   // clamp pad rows -> finite dups
        size_t g = gbase + (i / 7) * 56 + (i % 7);
        qf[mt] = *reinterpret_cast<const bf16x8*>(qkv + g * 768 +       h * 32 + quad * 8);
        kf[mt] = *reinterpret_cast<const bf16x8*>(qkv + g * 768 + 256 + h * 32 + quad * 8);
    }

    floatx4 s[4][4];
#pragma unroll
    for (int mt = 0; mt < 4; mt++)
#pragma unroll
        for (int nt = 0; nt < 4; nt++) {
            floatx4 z = {};
            s[mt][nt] = __builtin_amdgcn_mfma_f32_16x16x32_bf16(qf[mt], kf[nt], z, 0, 0, 0);
        }

#pragma unroll
    for (int mt = 0; mt < 4; mt++) {
#pragma unroll
        for (int r = 0; r < 4; r++) {
            float mx = -1e30f;
#pragma unroll
            for (int nt = 0; nt < 4; nt++) {
                int col = nt * 16 + l16;
                float v = (col < 49) ? s[mt][nt][r] * ATTN_SCALE : -1e30f;
                s[mt][nt][r] = v;
                mx = fmaxf(mx, v);
            }
#pragma unroll
            for (int off = 1; off < 16; off <<= 1) mx = fmaxf(mx, __shfl_xor(mx, off, 64));
            float sum = 0.f;
#pragma unroll
            for (int nt = 0; nt < 4; nt++) {
                float e = __expf(s[mt][nt][r] - mx);
                s[mt][nt][r] = e;
                sum += e;
            }
#pragma unroll
            for (int off = 1; off < 16; off <<= 1) sum += __shfl_xor(sum, off, 64);
            float inv = 1.0f / sum;
            int prow = mt * 16 + quad * 4 + r;
#pragma unroll
            for (int nt = 0; nt < 4; nt++)
                P[prow * 72 + nt * 16 + l16] = (bf16)(s[mt][nt][r] * inv);
        }
    }

    __syncthreads();

    floatx4 o[4][2] = {};
#pragma unroll
    for (int ks = 0; ks < 2; ks++) {
        bf16x8 pf[4], vf[2];
#pragma unroll
        for (int mt = 0; mt < 4; mt++)
            pf[mt] = *reinterpret_cast<const bf16x8*>(&P[(mt * 16 + l16) * 72 + ks * 32 + quad * 8]);
#pragma unroll
        for (int nt = 0; nt < 2; nt++)
            vf[nt] = *reinterpret_cast<const bf16x8*>(&VT[(nt * 16 + l16) * 72 + ks * 32 + quad * 8]);
#pragma unroll
        for (int mt = 0; mt < 4; mt++)
#pragma unroll
            for (int nt = 0; nt < 2; nt++)
                o[mt][nt] = __builtin_amdgcn_mfma_f32_16x16x32_bf16(pf[mt], vf[nt], o[mt][nt], 0, 0, 0);
    }

#pragma unroll
    for (int mt = 0; mt < 4; mt++) {
#pragma unroll
        for (int r = 0; r < 4; r++) {
            int i = mt * 16 + quad * 4 + r;
            if (i < 49) {
                size_t g = gbase + (i / 7) * 56 + (i % 7);
#pragma unroll
                for (int nt = 0; nt < 2; nt++) {
                    size_t adr = g * CDIM + h * 32 + nt * 16 + l16;
                    x1[adr] = X[adr] + o[mt][nt][r];
                }
            }
        }
    }
}

// ---------------- launcher ----------------
// ws: qkv_wt(0.4MB) fc1_wt(0.5MB) fc2_wt(0.5MB) | xn/x1n shared (51.4MB) |
//     union(qkvb 154MB, hbuf 205.5MB) -> ~258.4 MB total. x1 lives in d_out (fp32).
// (identical to the proven 818us layout)
extern "C" void kernel_launch(void* const* d_in, const int* in_sizes, int n_in,
                              void* d_out, int out_size, void* d_ws, size_t ws_size,
                              hipStream_t stream) {
    const float* x      = (const float*)d_in[0];
    const float* ln1_g  = (const float*)d_in[1];
    const float* ln1_b  = (const float*)d_in[2];
    const float* qkv_w  = (const float*)d_in[3];
    const float* qkv_b  = (const float*)d_in[4];
    const float* ln2_g  = (const float*)d_in[5];
    const float* ln2_b  = (const float*)d_in[6];
    const float* fc1_w  = (const float*)d_in[7];
    const float* fc1_b  = (const float*)d_in[8];
    const float* mlp_g  = (const float*)d_in[9];
    const float* mlp_b  = (const float*)d_in[10];
    const float* fc2_w  = (const float*)d_in[11];
    const float* fc2_b  = (const float*)d_in[12];
    float* out = (float*)d_out;

    char* ws = (char*)d_ws;
    bf16* qkv_wt = (bf16*)ws;  ws += (size_t)768 * 256 * 2;
    bf16* fc1_wt = (bf16*)ws;  ws += (size_t)1024 * 256 * 2;
    bf16* fc2_wt = (bf16*)ws;  ws += (size_t)256 * 1024 * 2;
    bf16* xn     = (bf16*)ws;  ws += (size_t)MROWS * CDIM * 2;   // reused as x1n
    bf16* qkvb   = (bf16*)ws;                                     // union with hbuf
    bf16* hbuf   = (bf16*)ws;
    float* x1 = out;

    wt_kernel<<<768,  256, 0, stream>>>(qkv_w, qkv_wt, 256, 768);
    wt_kernel<<<1024, 256, 0, stream>>>(fc1_w, fc1_wt, 256, 1024);
    wt_kernel<<<1024, 256, 0, stream>>>(fc2_w, fc2_wt, 1024, 256);

    ln_apply_f32_kernel<<<MROWS / 4, 256, 0, stream>>>(x, ln1_g, ln1_b, xn);
    gemm_bt_kernel<0, bf16><<<dim3(768 / 128, MROWS / 128), 256, 0, stream>>>(
        xn, qkv_wt, qkv_b, nullptr, qkvb, 768, 256);
    attn_kernel<<<BATCH * 64 * 2, 256, 0, stream>>>(qkvb, x, x1);
    ln_apply_f32_kernel<<<MROWS / 4, 256, 0, stream>>>(x1, ln2_g, ln2_b, xn);
    gemm_bt_kernel<1, bf16><<<dim3(HIDD / 128, MROWS / 128), 256, 0, stream>>>(
        xn, fc1_wt, fc1_b, nullptr, hbuf, HIDD, 256);
    ln_inplace_h_kernel<<<MROWS / 4, 256, 0, stream>>>(hbuf, mlp_g, mlp_b);
    gemm_bt_kernel<2, float><<<dim3(CDIM / 128, MROWS / 128), 256, 0, stream>>>(
        hbuf, fc2_wt, fc2_b, x1, out, CDIM, 1024);
}

// Round 5
// 719.828 us; speedup vs baseline: 1.1395x; 1.0512x over previous
//
#include <hip/hip_runtime.h>
#include <cmath>

// ---- TwinsBlock: B=32, H=W=56, C=256, heads=8, ws=7. fp32 I/O, bf16 MFMA ----
// R5: R4 (756us, proven) + mlp-LN folded into fc2.
//   - ln_inplace_h (~70us, 411MB traffic) deleted on the fused path; replaced by
//     a READ-ONLY hstats kernel (mean,rstd per row; 205.5MB read, mostly
//     L3-resident, 0.8MB write) + LN affine applied in fc2's epilogue
//     (g pre-folded into fc2 weights; c1/c2 column corrections precomputed).
//   - Workspace tail (838KB: mr/c12p/c12) is guarded by an adaptive ws_size
//     check; fallback path is byte-identical to R4. No layout can OOB.
//   - fc1 epilogue untouched (no atomics/shuffles — avoids regressing the
//     183us dispatch). GEMM main loop and all other kernels identical to R4.
typedef __bf16 bf16;
typedef __bf16 bf16x4 __attribute__((ext_vector_type(4)));
typedef __bf16 bf16x8 __attribute__((ext_vector_type(8)));
typedef float floatx4 __attribute__((ext_vector_type(4)));

constexpr int BATCH = 32;
constexpr int NTOK  = 3136;            // 56*56
constexpr int CDIM  = 256;
constexpr int MROWS = BATCH * NTOK;    // 100352
constexpr int HIDD  = 1024;
constexpr float ATTN_SCALE = 0.17677669529663689f;  // 32^-0.5

// tanh-form GELU: x * sigmoid(1.5957691*(x + 0.044715 x^3)). |err| ~3e-3,
// below the bf16 rounding already applied to h. ~6 VALU ops vs ~30 for erff.
__device__ __forceinline__ float gelu_fast(float x) {
    float p = fmaf(0.044715f * x, x * x, x);
    return __fdividef(x, 1.0f + __expf(-1.5957691216057308f * p));
}

__device__ __forceinline__ void load8(const bf16* p, float* o) {
    bf16x8 v = *reinterpret_cast<const bf16x8*>(p);
#pragma unroll
    for (int j = 0; j < 8; j++) o[j] = (float)v[j];
}

// async global->LDS, 16B per lane, wave-uniform LDS base + lane*16
__device__ __forceinline__ void gload_lds16(const void* g, void* l) {
    __builtin_amdgcn_global_load_lds(
        (const __attribute__((address_space(1))) void*)g,
        (__attribute__((address_space(3))) void*)l, 16, 0, 0);
}

// ---------------- weight convert + transpose: fp32 [K,N] -> bf16 [N,K] ----------------
// gsc != nullptr: scale row k by gsc[k] (folds mlp_ln_g into fc2 weights).
__global__ __launch_bounds__(256) void wt_kernel(
    const float* __restrict__ Win, bf16* __restrict__ Wt, int Ksz, int Nsz,
    const float* __restrict__ gsc)
{
    int id = blockIdx.x * 256 + threadIdx.x;       // over N*K, write-coalesced
    int n = id / Ksz, k = id % Ksz;
    float v = Win[(size_t)k * Nsz + n];
    if (gsc) v *= gsc[k];
    Wt[id] = (bf16)v;
}

// ---------------- c1/c2 column corrections for folded mlp-LN ----------------
// c1[n] = sum_k mlp_b[k]*W[k,n]; c2[n] = sum_k mlp_g[k]*W[k,n].  (fp32 exact)
__global__ __launch_bounds__(256) void c12_part_kernel(
    const float* __restrict__ W, const float* __restrict__ g,
    const float* __restrict__ b, float2* __restrict__ part)   // part[16][256]
{
    int n = threadIdx.x, j = blockIdx.x;
    float c1 = 0.f, c2 = 0.f;
#pragma unroll 8
    for (int k = j * 64; k < j * 64 + 64; k++) {
        float w = W[(size_t)k * 256 + n];
        c1 = fmaf(b[k], w, c1);
        c2 = fmaf(g[k], w, c2);
    }
    part[j * 256 + n] = make_float2(c1, c2);
}

__global__ __launch_bounds__(256) void c12_red_kernel(
    const float2* __restrict__ part, float2* __restrict__ c12)
{
    int n = threadIdx.x;
    float c1 = 0.f, c2 = 0.f;
#pragma unroll
    for (int j = 0; j < 16; j++) { float2 p = part[j * 256 + n]; c1 += p.x; c2 += p.y; }
    c12[n] = make_float2(c1, c2);
}

// ---------------- fused LN (stats+apply): fp32 [M,256] -> bf16 [M,256] ----------------
__global__ __launch_bounds__(256) void ln_apply_f32_kernel(
    const float* __restrict__ X, const float* __restrict__ g,
    const float* __restrict__ b, bf16* __restrict__ Y)
{
    int tok  = (blockIdx.x * 256 + threadIdx.x) >> 6;   // one wave per token
    int lane = threadIdx.x & 63;
    const float* row = X + (size_t)tok * CDIM;
    float4 v = *reinterpret_cast<const float4*>(row + lane * 4);
    float s  = v.x + v.y + v.z + v.w;
    float ss = v.x * v.x + v.y * v.y + v.z * v.z + v.w * v.w;
#pragma unroll
    for (int off = 32; off > 0; off >>= 1) {
        s  += __shfl_xor(s,  off, 64);
        ss += __shfl_xor(ss, off, 64);
    }
    float mean = s * (1.0f / CDIM);
    float var  = ss * (1.0f / CDIM) - mean * mean;
    if (var < 0.f) var = 0.f;
    float rstd = rsqrtf(var + 1e-5f);
    float4 gg = *reinterpret_cast<const float4*>(g + lane * 4);
    float4 bb = *reinterpret_cast<const float4*>(b + lane * 4);
    bf16x4 o;
    o[0] = (bf16)((v.x - mean) * rstd * gg.x + bb.x);
    o[1] = (bf16)((v.y - mean) * rstd * gg.y + bb.y);
    o[2] = (bf16)((v.z - mean) * rstd * gg.z + bb.z);
    o[3] = (bf16)((v.w - mean) * rstd * gg.w + bb.w);
    *reinterpret_cast<bf16x4*>(Y + (size_t)tok * CDIM + lane * 4) = o;
}

// ---------------- read-only row stats over bf16 [M,1024] -> (mean, rstd) ----------------
__global__ __launch_bounds__(256) void hstats_kernel(
    const bf16* __restrict__ H, float2* __restrict__ mr)
{
    int tok  = (blockIdx.x * 256 + threadIdx.x) >> 6;   // one wave per row
    int lane = threadIdx.x & 63;
    const bf16* row = H + (size_t)tok * HIDD;
    float f[16];
    load8(row + lane * 8, f);
    load8(row + 512 + lane * 8, f + 8);
    float s = 0.f, ss = 0.f;
#pragma unroll
    for (int j = 0; j < 16; j++) { s += f[j]; ss += f[j] * f[j]; }
#pragma unroll
    for (int off = 32; off > 0; off >>= 1) {
        s  += __shfl_xor(s,  off, 64);
        ss += __shfl_xor(ss, off, 64);
    }
    float mean = s * (1.0f / HIDD);
    float var  = ss * (1.0f / HIDD) - mean * mean;
    if (var < 0.f) var = 0.f;
    if (lane == 0) mr[tok] = make_float2(mean, rsqrtf(var + 1e-5f));
}

// ---------------- fallback: fused LN in-place over bf16 [M,1024] ----------------
__global__ __launch_bounds__(256) void ln_inplace_h_kernel(
    bf16* __restrict__ H, const float* __restrict__ g, const float* __restrict__ b)
{
    int tok  = (blockIdx.x * 256 + threadIdx.x) >> 6;
    int lane = threadIdx.x & 63;
    bf16* row = H + (size_t)tok * HIDD;
    float f[16];
    load8(row + lane * 8, f);
    load8(row + 512 + lane * 8, f + 8);
    float s = 0.f, ss = 0.f;
#pragma unroll
    for (int j = 0; j < 16; j++) { s += f[j]; ss += f[j] * f[j]; }
#pragma unroll
    for (int off = 32; off > 0; off >>= 1) {
        s  += __shfl_xor(s,  off, 64);
        ss += __shfl_xor(ss, off, 64);
    }
    float mean = s * (1.0f / HIDD);
    float var  = ss * (1.0f / HIDD) - mean * mean;
    if (var < 0.f) var = 0.f;
    float rstd = rsqrtf(var + 1e-5f);
    bf16x8 o0, o1;
#pragma unroll
    for (int j = 0; j < 8; j++) {
        o0[j] = (bf16)((f[j]     - mean) * rstd * g[lane * 8 + j]       + b[lane * 8 + j]);
        o1[j] = (bf16)((f[j + 8] - mean) * rstd * g[512 + lane * 8 + j] + b[512 + lane * 8 + j]);
    }
    *reinterpret_cast<bf16x8*>(row + lane * 8) = o0;
    *reinterpret_cast<bf16x8*>(row + 512 + lane * 8) = o1;
}

// ---------------- m97-style GEMM: out = epi( A[M,K] @ Bt[N,K]^T + bias ) ----------------
// 128x128 tile, BK=64, 4 waves (2x2), each 64x64 via 4x4 of mfma_f32_16x16x32_bf16.
// Both operands staged via global_load_lds width=16.
// EPI 0: bias. EPI 1: bias+GELU. EPI 2: folded mlp-LN
// (rstd*acc - mean*rstd*c2 + c1 + bias) + resid. EPI 3: bias + resid (fallback).
// XCD swizzle: consecutive same-XCD blocks share the A-tile (nwg%8==0 for all
// grids: qkv 6*784, fc1 8*784, fc2 2*784).
template<int EPI, typename TO>
__global__ __launch_bounds__(256) void gemm_bt_kernel(
    const bf16* __restrict__ A, const bf16* __restrict__ Bt,
    const float* __restrict__ bias, const float* __restrict__ resid,
    TO* __restrict__ out, int Nsz, int Ksz,
    const float2* __restrict__ mr, const float2* __restrict__ c12)
{
    __shared__ bf16 lA[128 * 64];   // [m][k], pitch 64 (global_load_lds needs contiguity)
    __shared__ bf16 lB[128 * 64];   // [n][k]
    const int t = threadIdx.x;
    const int lane = t & 63, w = t >> 6;
    const int quad = lane >> 4, l16 = lane & 15;
    const int wm = (w >> 1) * 64, wn = (w & 1) * 64;

    const int gx   = gridDim.x;
    const int flat = blockIdx.y * gx + blockIdx.x;
    const int cpx  = (gx * gridDim.y) >> 3;            // blocks per XCD
    const int fl2  = (flat & 7) * cpx + (flat >> 3);   // bijective (nwg%8==0)
    const int bx   = fl2 % gx, by = fl2 / gx;

    const size_t m0 = (size_t)by * 128;
    const int n0 = bx * 128;
    const int srow = w * 32 + (lane >> 3);   // staging: 8 lanes per 64-elem row
    const int scol = (lane & 7) * 8;

    floatx4 acc[4][4] = {};

    for (int kc = 0; kc < Ksz; kc += 64) {
#pragma unroll
        for (int j = 0; j < 4; j++) {
            gload_lds16(A  + (m0 + srow + j * 8) * Ksz + kc + scol, &lA[(w * 32 + j * 8) * 64]);
            gload_lds16(Bt + (size_t)(n0 + srow + j * 8) * Ksz + kc + scol, &lB[(w * 32 + j * 8) * 64]);
        }
        __syncthreads();
#pragma unroll
        for (int ks = 0; ks < 64; ks += 32) {
            bf16x8 af[4], bfv[4];
#pragma unroll
            for (int i = 0; i < 4; i++) {
                af[i]  = *reinterpret_cast<const bf16x8*>(&lA[(wm + i * 16 + l16) * 64 + ks + quad * 8]);
                bfv[i] = *reinterpret_cast<const bf16x8*>(&lB[(wn + i * 16 + l16) * 64 + ks + quad * 8]);
            }
#pragma unroll
            for (int mi = 0; mi < 4; mi++)
#pragma unroll
                for (int ni = 0; ni < 4; ni++)
                    acc[mi][ni] = __builtin_amdgcn_mfma_f32_16x16x32_bf16(af[mi], bfv[ni], acc[mi][ni], 0, 0, 0);
        }
        __syncthreads();
    }

    float bcol[4];
    float2 cc[4];
#pragma unroll
    for (int ni = 0; ni < 4; ni++) {
        int col = n0 + wn + ni * 16 + l16;
        bcol[ni] = bias[col];
        if (EPI == 2) cc[ni] = c12[col];
    }

#pragma unroll
    for (int mi = 0; mi < 4; mi++) {
#pragma unroll
        for (int r = 0; r < 4; r++) {
            size_t row = m0 + wm + mi * 16 + quad * 4 + r;   // C/D: row=quad*4+reg
            float sc = 0.f, ofs = 0.f;
            if (EPI == 2) {
                float2 mv = mr[row];
                sc  = mv.y;            // rstd
                ofs = -mv.x * mv.y;    // -mean*rstd
            }
#pragma unroll
            for (int ni = 0; ni < 4; ni++) {
                int col = n0 + wn + ni * 16 + l16;
                float v;
                if (EPI == 0) {
                    v = acc[mi][ni][r] + bcol[ni];
                } else if (EPI == 1) {
                    v = gelu_fast(acc[mi][ni][r] + bcol[ni]);
                } else if (EPI == 2) {
                    float base = fmaf(ofs, cc[ni].y, cc[ni].x + bcol[ni]);
                    v = fmaf(sc, acc[mi][ni][r], base);
                    v += resid[row * (size_t)Nsz + col];
                } else {
                    v = acc[mi][ni][r] + bcol[ni] + resid[row * (size_t)Nsz + col];
                }
                out[row * (size_t)Nsz + col] = (TO)v;
            }
        }
    }
}

// ---------------- windowed attention, one wave = one (batch, window, head) ----------------
__global__ __launch_bounds__(256) void attn_kernel(
    const bf16* __restrict__ qkv, const float* __restrict__ X,
    float* __restrict__ x1)
{
    __shared__ bf16 pbuf[4][64 * 72];   // P[i][j], per wave
    __shared__ bf16 vtbuf[4][32 * 72];  // V^T[d][j], per wave
    const int w = threadIdx.x >> 6, lane = threadIdx.x & 63;
    const int quad = lane >> 4, l16 = lane & 15;
    const int blk = blockIdx.x;
    const int hg = blk & 1, p = (blk >> 1) & 63, b = blk >> 7;
    const int h = hg * 4 + w;
    const int py = p >> 3, px = p & 7;
    const size_t gbase = (size_t)b * NTOK + py * 7 * 56 + px * 7;
    bf16* P  = pbuf[w];
    bf16* VT = vtbuf[w];

    unsigned int* vz = (unsigned int*)VT;
    for (int i = lane; i < 32 * 72 / 2; i += 64) vz[i] = 0u;

    for (int idx = lane; idx < 49 * 4; idx += 64) {
        int tk = idx >> 2, d8 = (idx & 3) * 8;
        size_t g = gbase + (tk / 7) * 56 + (tk % 7);
        bf16x8 vv = *reinterpret_cast<const bf16x8*>(qkv + g * 768 + 512 + h * 32 + d8);
#pragma unroll
        for (int j = 0; j < 8; j++) VT[(d8 + j) * 72 + tk] = vv[j];
    }

    bf16x8 qf[4], kf[4];
#pragma unroll
    for (int mt = 0; mt < 4; mt++) {
        int i = mt * 16 + l16; if (i > 48) i = 48;   // clamp pad rows -> finite dups
        size_t g = gbase + (i / 7) * 56 + (i % 7);
        qf[mt] = *reinterpret_cast<const bf16x8*>(qkv + g * 768 +       h * 32 + quad * 8);
        kf[mt] = *reinterpret_cast<const bf16x8*>(qkv + g * 768 + 256 + h * 32 + quad * 8);
    }

    floatx4 s[4][4];
#pragma unroll
    for (int mt = 0; mt < 4; mt++)
#pragma unroll
        for (int nt = 0; nt < 4; nt++) {
            floatx4 z = {};
            s[mt][nt] = __builtin_amdgcn_mfma_f32_16x16x32_bf16(qf[mt], kf[nt], z, 0, 0, 0);
        }

#pragma unroll
    for (int mt = 0; mt < 4; mt++) {
#pragma unroll
        for (int r = 0; r < 4; r++) {
            float mx = -1e30f;
#pragma unroll
            for (int nt = 0; nt < 4; nt++) {
                int col = nt * 16 + l16;
                float v = (col < 49) ? s[mt][nt][r] * ATTN_SCALE : -1e30f;
                s[mt][nt][r] = v;
                mx = fmaxf(mx, v);
            }
#pragma unroll
            for (int off = 1; off < 16; off <<= 1) mx = fmaxf(mx, __shfl_xor(mx, off, 64));
            float sum = 0.f;
#pragma unroll
            for (int nt = 0; nt < 4; nt++) {
                float e = __expf(s[mt][nt][r] - mx);
                s[mt][nt][r] = e;
                sum += e;
            }
#pragma unroll
            for (int off = 1; off < 16; off <<= 1) sum += __shfl_xor(sum, off, 64);
            float inv = 1.0f / sum;
            int prow = mt * 16 + quad * 4 + r;
#pragma unroll
            for (int nt = 0; nt < 4; nt++)
                P[prow * 72 + nt * 16 + l16] = (bf16)(s[mt][nt][r] * inv);
        }
    }

    __syncthreads();

    floatx4 o[4][2] = {};
#pragma unroll
    for (int ks = 0; ks < 2; ks++) {
        bf16x8 pf[4], vf[2];
#pragma unroll
        for (int mt = 0; mt < 4; mt++)
            pf[mt] = *reinterpret_cast<const bf16x8*>(&P[(mt * 16 + l16) * 72 + ks * 32 + quad * 8]);
#pragma unroll
        for (int nt = 0; nt < 2; nt++)
            vf[nt] = *reinterpret_cast<const bf16x8*>(&VT[(nt * 16 + l16) * 72 + ks * 32 + quad * 8]);
#pragma unroll
        for (int mt = 0; mt < 4; mt++)
#pragma unroll
            for (int nt = 0; nt < 2; nt++)
                o[mt][nt] = __builtin_amdgcn_mfma_f32_16x16x32_bf16(pf[mt], vf[nt], o[mt][nt], 0, 0, 0);
    }

#pragma unroll
    for (int mt = 0; mt < 4; mt++) {
#pragma unroll
        for (int r = 0; r < 4; r++) {
            int i = mt * 16 + quad * 4 + r;
            if (i < 49) {
                size_t g = gbase + (i / 7) * 56 + (i % 7);
#pragma unroll
                for (int nt = 0; nt < 2; nt++) {
                    size_t adr = g * CDIM + h * 32 + nt * 16 + l16;
                    x1[adr] = X[adr] + o[mt][nt][r];
                }
            }
        }
    }
}

// ---------------- launcher ----------------
// Base layout (identical to the proven 756us run, 258,342,912 B):
//   qkv_wt 0.39MB | fc1_wt 0.52MB | fc2_wt 0.52MB | xn 51.38MB |
//   union(qkvb 154MB, hbuf 205.5MB)
// Optional tail (837,632 B): mr[MROWS] f2 | c12p[16*256] f2 | c12[256] f2
//   -> used only when ws_size has room. x1 lives in d_out (fp32).
extern "C" void kernel_launch(void* const* d_in, const int* in_sizes, int n_in,
                              void* d_out, int out_size, void* d_ws, size_t ws_size,
                              hipStream_t stream) {
    const float* x      = (const float*)d_in[0];
    const float* ln1_g  = (const float*)d_in[1];
    const float* ln1_b  = (const float*)d_in[2];
    const float* qkv_w  = (const float*)d_in[3];
    const float* qkv_b  = (const float*)d_in[4];
    const float* ln2_g  = (const float*)d_in[5];
    const float* ln2_b  = (const float*)d_in[6];
    const float* fc1_w  = (const float*)d_in[7];
    const float* fc1_b  = (const float*)d_in[8];
    const float* mlp_g  = (const float*)d_in[9];
    const float* mlp_b  = (const float*)d_in[10];
    const float* fc2_w  = (const float*)d_in[11];
    const float* fc2_b  = (const float*)d_in[12];
    float* out = (float*)d_out;

    char* ws = (char*)d_ws;
    bf16* qkv_wt = (bf16*)ws;  ws += (size_t)768 * 256 * 2;
    bf16* fc1_wt = (bf16*)ws;  ws += (size_t)1024 * 256 * 2;
    bf16* fc2_wt = (bf16*)ws;  ws += (size_t)256 * 1024 * 2;
    bf16* xn     = (bf16*)ws;  ws += (size_t)MROWS * CDIM * 2;   // reused as x1n
    bf16* qkvb   = (bf16*)ws;                                     // union with hbuf
    bf16* hbuf   = (bf16*)ws;  ws += (size_t)MROWS * HIDD * 2;

    const size_t base_bytes = (size_t)(ws - (char*)d_ws);          // 258,342,912
    const size_t tail_bytes = (size_t)MROWS * sizeof(float2)
                            + (size_t)16 * 256 * sizeof(float2)
                            + (size_t)256 * sizeof(float2);        // 837,632
    const bool fuse_ln = (ws_size >= base_bytes + tail_bytes);

    float2* mr   = (float2*)ws;
    float2* c12p = mr + MROWS;
    float2* c12  = c12p + 16 * 256;
    float* x1 = out;

    // weight prep
    wt_kernel<<<768,  256, 0, stream>>>(qkv_w, qkv_wt, 256, 768, nullptr);
    wt_kernel<<<1024, 256, 0, stream>>>(fc1_w, fc1_wt, 256, 1024, nullptr);
    wt_kernel<<<1024, 256, 0, stream>>>(fc2_w, fc2_wt, 1024, 256,
                                        fuse_ln ? mlp_g : nullptr);
    if (fuse_ln) {
        c12_part_kernel<<<16, 256, 0, stream>>>(fc2_w, mlp_g, mlp_b, c12p);
        c12_red_kernel<<<1, 256, 0, stream>>>(c12p, c12);
    }

    ln_apply_f32_kernel<<<MROWS / 4, 256, 0, stream>>>(x, ln1_g, ln1_b, xn);
    gemm_bt_kernel<0, bf16><<<dim3(768 / 128, MROWS / 128), 256, 0, stream>>>(
        xn, qkv_wt, qkv_b, nullptr, qkvb, 768, 256, nullptr, nullptr);
    attn_kernel<<<BATCH * 64 * 2, 256, 0, stream>>>(qkvb, x, x1);
    ln_apply_f32_kernel<<<MROWS / 4, 256, 0, stream>>>(x1, ln2_g, ln2_b, xn);
    gemm_bt_kernel<1, bf16><<<dim3(HIDD / 128, MROWS / 128), 256, 0, stream>>>(
        xn, fc1_wt, fc1_b, nullptr, hbuf, HIDD, 256, nullptr, nullptr);

    if (fuse_ln) {
        hstats_kernel<<<MROWS / 4, 256, 0, stream>>>(hbuf, mr);
        gemm_bt_kernel<2, float><<<dim3(CDIM / 128, MROWS / 128), 256, 0, stream>>>(
            hbuf, fc2_wt, fc2_b, x1, out, CDIM, 1024, mr, c12);
    } else {
        ln_inplace_h_kernel<<<MROWS / 4, 256, 0, stream>>>(hbuf, mlp_g, mlp_b);
        gemm_bt_kernel<3, float><<<dim3(CDIM / 128, MROWS / 128), 256, 0, stream>>>(
            hbuf, fc2_wt, fc2_b, x1, out, CDIM, 1024, nullptr, nullptr);
    }
}